// Round 4
// baseline (1607.225 us; speedup 1.0000x reference)
//
#include <hip/hip_runtime.h>
#include <stdint.h>

typedef __attribute__((ext_vector_type(8))) short short8;
typedef __attribute__((ext_vector_type(4))) float float4v;
typedef __attribute__((ext_vector_type(2))) unsigned int uint2v;

#define BM 128
#define BN 128
#define BK 32
#define LDT 40   // padded LDS row stride (ushorts): 80B -> bank stride 20 mod 32

__device__ __forceinline__ unsigned short f2bf(float f) {
    union { float f; unsigned u; } x; x.f = f;
    unsigned u = x.u;
    u += 0x7fffu + ((u >> 16) & 1u);   // RNE
    return (unsigned short)(u >> 16);
}
__device__ __forceinline__ float bf2f(unsigned short s) {
    union { unsigned u; float f; } x; x.u = ((unsigned)s) << 16;
    return x.f;
}

// ---- transpose fp32 weight [K][256] -> bf16 [256][K] ----
__global__ __launch_bounds__(256) void transpose_bf16_kernel(
    const float* __restrict__ W, unsigned short* __restrict__ WT, int K, int N)
{
    int idx = blockIdx.x * 256 + threadIdx.x;
    if (idx < K * N) {
        int k = idx / N, n = idx - k * N;
        WT[(size_t)n * K + k] = f2bf(W[idx]);
    }
}

// ---- GEMM1: X(concat) @ W1 -> H1 (bf16) + column partial sum/sumsq ----
// 2-phase pipeline: double-buffered LDS A, reg-prefetched A+B, B direct from L2.
__global__ __launch_bounds__(256) void gemm1_kernel(
    const float* __restrict__ src, const float* __restrict__ dst,
    const float* __restrict__ edge, const float* __restrict__ u,
    const int* __restrict__ batch, const unsigned short* __restrict__ W1T,
    unsigned short* __restrict__ H1, float* __restrict__ psum,
    float* __restrict__ psq, int E, int MT)
{
    __shared__ __align__(16) unsigned short lsA[2][BM * LDT];
    __shared__ int lsBatch[BM];
    __shared__ float ldsS[4][64];
    __shared__ float ldsQ[4][64];

    const int t = threadIdx.x;
    const int bm = blockIdx.x, bn = blockIdx.y;
    const int lane = t & 63, w = t >> 6;
    const int wm = w >> 1, wn = w & 1;
    const int quad = lane >> 4, l16 = lane & 15;

    if (t < BM) {
        int grow = bm * BM + t; if (grow >= E) grow = E - 1;
        lsBatch[t] = batch[grow];
    }

    float4v acc[4][4] = {};

    const int tc = t & 7, tr0 = t >> 3;
    const int n0 = bn * BN;
    const unsigned short* Bbase = W1T + (size_t)(n0 + wn * 64 + l16) * 384 + quad * 8;

    float4v aCur[4]; short8 bCur[4];

    // ---- prologue: tile kk=0 (pure src, no batch dependency) ----
    #pragma unroll
    for (int i = 0; i < 4; i++) {
        int rl = tr0 + 32 * i;
        int grow = bm * BM + rl; if (grow >= E) grow = E - 1;
        aCur[i] = *(const float4v*)(src + (size_t)grow * 128 + tc * 4);
    }
    #pragma unroll
    for (int x = 0; x < 4; x++)
        bCur[x] = *(const short8*)(Bbase + (size_t)x * 16 * 384);
    #pragma unroll
    for (int i = 0; i < 4; i++) {
        int rl = tr0 + 32 * i;
        unsigned lo = (unsigned)f2bf(aCur[i][0]) | ((unsigned)f2bf(aCur[i][1]) << 16);
        unsigned hi = (unsigned)f2bf(aCur[i][2]) | ((unsigned)f2bf(aCur[i][3]) << 16);
        uint2v v2; v2.x = lo; v2.y = hi;
        *(uint2v*)&lsA[0][rl * LDT + tc * 4] = v2;
    }
    __syncthreads();

    int cur = 0;
    #pragma unroll 1
    for (int kk = 0; kk < 12; kk++) {
        float4v aN[4]; short8 bN[4];
        const bool pf = (kk < 11);
        if (pf) {
            const int k1 = kk + 1;
            const int kc2 = k1 * BK;
            // uniform source-bucket select, hoisted out of the row loop
            const float* base; int rstride, coff;
            bool isU = false;
            if (k1 < 4)       { base = src;  rstride = 128; coff = kc2; }
            else if (k1 < 8)  { base = dst;  rstride = 128; coff = kc2 - 128; }
            else if (k1 < 10) { base = edge; rstride = 64;  coff = kc2 - 256; }
            else              { base = u;    rstride = 64;  coff = kc2 - 320; isU = true; }
            #pragma unroll
            for (int i = 0; i < 4; i++) {
                int rl = tr0 + 32 * i;
                int grow = bm * BM + rl; if (grow >= E) grow = E - 1;
                int r = isU ? lsBatch[rl] : grow;
                aN[i] = *(const float4v*)(base + (size_t)r * rstride + coff + tc * 4);
            }
            #pragma unroll
            for (int x = 0; x < 4; x++)
                bN[x] = *(const short8*)(Bbase + (size_t)x * 16 * 384 + kc2);
        }
        // ---- compute on current buffer ----
        short8 af[4];
        #pragma unroll
        for (int x = 0; x < 4; x++)
            af[x] = *(const short8*)&lsA[cur][(wm * 64 + x * 16 + l16) * LDT + quad * 8];
        #pragma unroll
        for (int i = 0; i < 4; i++)
            #pragma unroll
            for (int j = 0; j < 4; j++)
                acc[i][j] = __builtin_amdgcn_mfma_f32_16x16x32_bf16(af[i], bCur[j], acc[i][j], 0, 0, 0);
        if (pf) {
            // ---- write next tile to the other buffer ----
            #pragma unroll
            for (int i = 0; i < 4; i++) {
                int rl = tr0 + 32 * i;
                unsigned lo = (unsigned)f2bf(aN[i][0]) | ((unsigned)f2bf(aN[i][1]) << 16);
                unsigned hi = (unsigned)f2bf(aN[i][2]) | ((unsigned)f2bf(aN[i][3]) << 16);
                uint2v v2; v2.x = lo; v2.y = hi;
                *(uint2v*)&lsA[cur ^ 1][rl * LDT + tc * 4] = v2;
            }
            #pragma unroll
            for (int x = 0; x < 4; x++) bCur[x] = bN[x];
            cur ^= 1;
            __syncthreads();
        }
    }

    // ---- epilogue: store H1 bf16, accumulate column stats ----
    float s[4] = {0.f,0.f,0.f,0.f}, q[4] = {0.f,0.f,0.f,0.f};
    #pragma unroll
    for (int i = 0; i < 4; i++) {
        #pragma unroll
        for (int r = 0; r < 4; r++) {
            int row = bm * BM + wm * 64 + i * 16 + quad * 4 + r;
            bool ok = row < E;
            #pragma unroll
            for (int j = 0; j < 4; j++) {
                float v = acc[i][j][r];
                int col = bn * BN + wn * 64 + j * 16 + l16;
                if (ok) {
                    H1[(size_t)row * 256 + col] = f2bf(v);
                    s[j] += v; q[j] += v * v;
                }
            }
        }
    }
    #pragma unroll
    for (int j = 0; j < 4; j++) {
        s[j] += __shfl_xor(s[j], 16, 64); s[j] += __shfl_xor(s[j], 32, 64);
        q[j] += __shfl_xor(q[j], 16, 64); q[j] += __shfl_xor(q[j], 32, 64);
    }
    if (quad == 0) {
        #pragma unroll
        for (int j = 0; j < 4; j++) { ldsS[w][j * 16 + l16] = s[j]; ldsQ[w][j * 16 + l16] = q[j]; }
    }
    __syncthreads();
    if (t < 128) {
        int g = t >> 6, i = t & 63;
        float S = ldsS[g][i] + ldsS[g + 2][i];
        float Q = ldsQ[g][i] + ldsQ[g + 2][i];
        int col = bn * BN + t;
        psum[(size_t)col * MT + bm] = S;
        psq [(size_t)col * MT + bm] = Q;
    }
}

// ---- reduce partials -> per-column affine a = g*rsqrt(v+eps), d = b - m*a ----
__global__ __launch_bounds__(256) void stats_kernel(
    const float* __restrict__ psum, const float* __restrict__ psq,
    const float* __restrict__ gamma, const float* __restrict__ beta,
    float* __restrict__ ad, int MT, float invE)
{
    __shared__ float rs[4], rq[4];
    int c = blockIdx.x;
    float s = 0.f, q = 0.f;
    for (int i = threadIdx.x; i < MT; i += 256) {
        s += psum[(size_t)c * MT + i];
        q += psq [(size_t)c * MT + i];
    }
    for (int off = 32; off >= 1; off >>= 1) {
        s += __shfl_xor(s, off, 64);
        q += __shfl_xor(q, off, 64);
    }
    int lane = threadIdx.x & 63, w = threadIdx.x >> 6;
    if (lane == 0) { rs[w] = s; rq[w] = q; }
    __syncthreads();
    if (threadIdx.x == 0) {
        float S = rs[0] + rs[1] + rs[2] + rs[3];
        float Q = rq[0] + rq[1] + rq[2] + rq[3];
        float m = S * invE;
        float v = Q * invE - m * m;
        float a = gamma[c] * rsqrtf(v + 1e-5f);
        ad[c] = a;
        ad[256 + c] = beta[c] - m * a;
    }
}

// ---- GEMM2: relu(a1*H1+d1) @ W2 -> out (pre-BN fp32) + column partials ----
// Same 2-phase pipeline as gemm1.
__global__ __launch_bounds__(256) void gemm2_kernel(
    const unsigned short* __restrict__ H1, const unsigned short* __restrict__ W2T,
    const float* __restrict__ ad1, float* __restrict__ out,
    float* __restrict__ psum, float* __restrict__ psq, int E, int MT)
{
    __shared__ __align__(16) unsigned short lsA[2][BM * LDT];
    __shared__ float ldsS[4][64];
    __shared__ float ldsQ[4][64];

    const int t = threadIdx.x;
    const int bm = blockIdx.x, bn = blockIdx.y;
    const int lane = t & 63, w = t >> 6;
    const int wm = w >> 1, wn = w & 1;
    const int quad = lane >> 4, l16 = lane & 15;

    float4v acc[4][4] = {};

    const int kq = (t & 3) * 8, rb = t >> 2;
    const int n0 = bn * BN;
    const unsigned short* Bbase = W2T + (size_t)(n0 + wn * 64 + l16) * 256 + quad * 8;

    short8 hCur[2]; float4v adC[4]; short8 bCur[4];

    // ---- prologue: tile kk=0 ----
    adC[0] = *(const float4v*)(ad1 + kq);
    adC[1] = *(const float4v*)(ad1 + kq + 4);
    adC[2] = *(const float4v*)(ad1 + 256 + kq);
    adC[3] = *(const float4v*)(ad1 + 256 + kq + 4);
    #pragma unroll
    for (int i = 0; i < 2; i++) {
        int rl = rb + 64 * i;
        int grow = bm * BM + rl; if (grow >= E) grow = E - 1;
        hCur[i] = *(const short8*)(H1 + (size_t)grow * 256 + kq);
    }
    #pragma unroll
    for (int x = 0; x < 4; x++)
        bCur[x] = *(const short8*)(Bbase + (size_t)x * 16 * 256);
    #pragma unroll
    for (int i = 0; i < 2; i++) {
        int rl = rb + 64 * i;
        short8 yv;
        #pragma unroll
        for (int e = 0; e < 4; e++) {
            float y = fmaxf(fmaf(bf2f((unsigned short)hCur[i][e]), adC[0][e], adC[2][e]), 0.f);
            yv[e] = (short)f2bf(y);
        }
        #pragma unroll
        for (int e = 0; e < 4; e++) {
            float y = fmaxf(fmaf(bf2f((unsigned short)hCur[i][4 + e]), adC[1][e], adC[3][e]), 0.f);
            yv[4 + e] = (short)f2bf(y);
        }
        *(short8*)&lsA[0][rl * LDT + kq] = yv;
    }
    __syncthreads();

    int cur = 0;
    #pragma unroll 1
    for (int kk = 0; kk < 8; kk++) {
        short8 hN[2]; float4v adN[4]; short8 bN[4];
        const bool pf = (kk < 7);
        if (pf) {
            const int kc2 = (kk + 1) * BK;
            adN[0] = *(const float4v*)(ad1 + kc2 + kq);
            adN[1] = *(const float4v*)(ad1 + kc2 + kq + 4);
            adN[2] = *(const float4v*)(ad1 + 256 + kc2 + kq);
            adN[3] = *(const float4v*)(ad1 + 256 + kc2 + kq + 4);
            #pragma unroll
            for (int i = 0; i < 2; i++) {
                int rl = rb + 64 * i;
                int grow = bm * BM + rl; if (grow >= E) grow = E - 1;
                hN[i] = *(const short8*)(H1 + (size_t)grow * 256 + kc2 + kq);
            }
            #pragma unroll
            for (int x = 0; x < 4; x++)
                bN[x] = *(const short8*)(Bbase + (size_t)x * 16 * 256 + kc2);
        }
        // ---- compute on current buffer ----
        short8 af[4];
        #pragma unroll
        for (int x = 0; x < 4; x++)
            af[x] = *(const short8*)&lsA[cur][(wm * 64 + x * 16 + l16) * LDT + quad * 8];
        #pragma unroll
        for (int i = 0; i < 4; i++)
            #pragma unroll
            for (int j = 0; j < 4; j++)
                acc[i][j] = __builtin_amdgcn_mfma_f32_16x16x32_bf16(af[i], bCur[j], acc[i][j], 0, 0, 0);
        if (pf) {
            #pragma unroll
            for (int i = 0; i < 2; i++) {
                int rl = rb + 64 * i;
                short8 yv;
                #pragma unroll
                for (int e = 0; e < 4; e++) {
                    float y = fmaxf(fmaf(bf2f((unsigned short)hN[i][e]), adN[0][e], adN[2][e]), 0.f);
                    yv[e] = (short)f2bf(y);
                }
                #pragma unroll
                for (int e = 0; e < 4; e++) {
                    float y = fmaxf(fmaf(bf2f((unsigned short)hN[i][4 + e]), adN[1][e], adN[3][e]), 0.f);
                    yv[4 + e] = (short)f2bf(y);
                }
                *(short8*)&lsA[cur ^ 1][rl * LDT + kq] = yv;
            }
            #pragma unroll
            for (int x = 0; x < 4; x++) bCur[x] = bN[x];
            cur ^= 1;
            __syncthreads();
        }
    }

    float s[4] = {0.f,0.f,0.f,0.f}, q[4] = {0.f,0.f,0.f,0.f};
    #pragma unroll
    for (int i = 0; i < 4; i++) {
        #pragma unroll
        for (int r = 0; r < 4; r++) {
            int row = bm * BM + wm * 64 + i * 16 + quad * 4 + r;
            bool ok = row < E;
            #pragma unroll
            for (int j = 0; j < 4; j++) {
                float v = acc[i][j][r];
                int col = bn * BN + wn * 64 + j * 16 + l16;
                if (ok) {
                    out[(size_t)row * 256 + col] = v;
                    s[j] += v; q[j] += v * v;
                }
            }
        }
    }
    #pragma unroll
    for (int j = 0; j < 4; j++) {
        s[j] += __shfl_xor(s[j], 16, 64); s[j] += __shfl_xor(s[j], 32, 64);
        q[j] += __shfl_xor(q[j], 16, 64); q[j] += __shfl_xor(q[j], 32, 64);
    }
    if (quad == 0) {
        #pragma unroll
        for (int j = 0; j < 4; j++) { ldsS[w][j * 16 + l16] = s[j]; ldsQ[w][j * 16 + l16] = q[j]; }
    }
    __syncthreads();
    if (t < 128) {
        int g = t >> 6, i = t & 63;
        float S = ldsS[g][i] + ldsS[g + 2][i];
        float Q = ldsQ[g][i] + ldsQ[g + 2][i];
        int col = bn * BN + t;
        psum[(size_t)col * MT + bm] = S;
        psq [(size_t)col * MT + bm] = Q;
    }
}

// ---- out = a2*out + d2 (in place) ----
__global__ __launch_bounds__(256) void finalize_kernel(
    float* __restrict__ out, const float* __restrict__ ad, long n4)
{
    long stride = (long)gridDim.x * 256;
    for (long i = (long)blockIdx.x * 256 + threadIdx.x; i < n4; i += stride) {
        float4v v = ((float4v*)out)[i];
        int c4 = (int)(i & 63);
        float4v a = ((const float4v*)ad)[c4];
        float4v d = ((const float4v*)(ad + 256))[c4];
        v = a * v + d;
        ((float4v*)out)[i] = v;
    }
}

extern "C" void kernel_launch(void* const* d_in, const int* in_sizes, int n_in,
                              void* d_out, int out_size, void* d_ws, size_t ws_size,
                              hipStream_t stream)
{
    const float* src  = (const float*)d_in[0];
    const float* dst  = (const float*)d_in[1];
    const float* edge = (const float*)d_in[2];
    const float* u    = (const float*)d_in[3];
    const int*   batch= (const int*)d_in[4];
    const float* W1   = (const float*)d_in[5];
    const float* g1   = (const float*)d_in[6];
    const float* b1   = (const float*)d_in[7];
    const float* W2   = (const float*)d_in[8];
    const float* g2   = (const float*)d_in[9];
    const float* b2   = (const float*)d_in[10];
    float* out = (float*)d_out;

    const int E  = in_sizes[0] / 128;
    const int MT = (E + BM - 1) / BM;

    char* ws = (char*)d_ws;
    size_t off = 0;
    auto alloc = [&](size_t bytes) -> void* {
        void* p = (void*)(ws + off);
        off += (bytes + 255) & ~(size_t)255;
        return p;
    };
    unsigned short* H1  = (unsigned short*)alloc((size_t)E * 256 * 2);
    unsigned short* W1T = (unsigned short*)alloc((size_t)256 * 384 * 2);
    unsigned short* W2T = (unsigned short*)alloc((size_t)256 * 256 * 2);
    float* psum = (float*)alloc((size_t)256 * MT * 4);
    float* psq  = (float*)alloc((size_t)256 * MT * 4);
    float* ad1  = (float*)alloc(512 * 4);
    float* ad2  = (float*)alloc(512 * 4);
    (void)ws_size; (void)n_in; (void)out_size;

    transpose_bf16_kernel<<<(384 * 256 + 255) / 256, 256, 0, stream>>>(W1, W1T, 384, 256);
    transpose_bf16_kernel<<<(256 * 256 + 255) / 256, 256, 0, stream>>>(W2, W2T, 256, 256);
    gemm1_kernel<<<dim3(MT, 2), 256, 0, stream>>>(src, dst, edge, u, batch, W1T, H1, psum, psq, E, MT);
    stats_kernel<<<256, 256, 0, stream>>>(psum, psq, g1, b1, ad1, MT, 1.0f / (float)E);
    gemm2_kernel<<<dim3(MT, 2), 256, 0, stream>>>(H1, W2T, ad1, out, psum, psq, E, MT);
    stats_kernel<<<256, 256, 0, stream>>>(psum, psq, g2, b2, ad2, MT, 1.0f / (float)E);
    const long n4 = (long)E * 64;
    finalize_kernel<<<16384, 256, 0, stream>>>(out, ad2, n4);
}

// Round 7
// 1513.607 us; speedup vs baseline: 1.0619x; 1.0619x over previous
//
#include <hip/hip_runtime.h>
#include <stdint.h>

typedef __attribute__((ext_vector_type(8))) short short8;
typedef __attribute__((ext_vector_type(4))) float float4v;

#define BM 128
#define BN 128
#define BK 32
#define LDT 40   // padded LDS row stride (ushorts): 80B -> bank stride 20 mod 32

__device__ __forceinline__ unsigned short f2bf(float f) {
    union { float f; unsigned u; } x; x.f = f;
    unsigned u = x.u;
    u += 0x7fffu + ((u >> 16) & 1u);   // RNE
    return (unsigned short)(u >> 16);
}
__device__ __forceinline__ float bf2f(unsigned short s) {
    union { unsigned u; float f; } x; x.u = ((unsigned)s) << 16;
    return x.f;
}

// ---- transpose fp32 weight [K][256] -> bf16 [256][K] ----
__global__ __launch_bounds__(256) void transpose_bf16_kernel(
    const float* __restrict__ W, unsigned short* __restrict__ WT, int K, int N)
{
    int idx = blockIdx.x * 256 + threadIdx.x;
    if (idx < K * N) {
        int k = idx / N, n = idx - k * N;
        WT[(size_t)n * K + k] = f2bf(W[idx]);
    }
}

// ---- GEMM1: X(concat) @ W1 -> H1 (bf16) + column partial sum/sumsq ----
// Round-0 structure (stage->barrier->MFMA->barrier), 512 threads / 8 waves,
// 64x32 wave tile: acc 32 AGPR -> <=128 unified regs -> 16 waves/CU.
__global__ __launch_bounds__(512, 4) void gemm1_kernel(
    const float* __restrict__ src, const float* __restrict__ dst,
    const float* __restrict__ edge, const float* __restrict__ u,
    const int* __restrict__ batch, const unsigned short* __restrict__ W1T,
    unsigned short* __restrict__ H1, float* __restrict__ psum,
    float* __restrict__ psq, int E, int MT)
{
    __shared__ __align__(16) unsigned short lsA[BM * LDT];
    __shared__ __align__(16) unsigned short lsB[BN * LDT];
    __shared__ int lsBatch[BM];
    __shared__ float ldsS[8][32];
    __shared__ float ldsQ[8][32];

    const int t = threadIdx.x;
    const int bm = blockIdx.x, bn = blockIdx.y;
    const int lane = t & 63, w = t >> 6;
    const int wm = w >> 2, wn = w & 3;          // 2 x 4 wave grid
    const int quad = lane >> 4, l16 = lane & 15;

    if (t < BM) {
        int grow = bm * BM + t; if (grow >= E) grow = E - 1;
        lsBatch[t] = batch[grow];
    }

    float4v acc[4][2] = {};

    const int tc = t & 7, tr0 = t >> 3;         // A staging: 8 float4 cols, 64 rows
    const int kq = (t & 3) * 8, nb = t >> 2;    // B staging: 4 col-groups, 128 rows
    const int n0 = bn * BN;

    for (int kk = 0; kk < 12; kk++) {
        const int kc = kk * BK;
        // ---- stage A: gather + fp32->bf16 (2 rows/thread) ----
        #pragma unroll
        for (int i = 0; i < 2; i++) {
            int rl = tr0 + 64 * i;
            int grow = bm * BM + rl; if (grow >= E) grow = E - 1;
            const float* p;
            if (kk < 4)       p = src  + (size_t)grow * 128 + kc + tc * 4;
            else if (kk < 8)  p = dst  + (size_t)grow * 128 + (kc - 128) + tc * 4;
            else if (kk < 10) p = edge + (size_t)grow * 64  + (kc - 256) + tc * 4;
            else              p = u + (size_t)lsBatch[rl] * 64 + (kc - 320) + tc * 4;
            float4v v = *(const float4v*)p;
            unsigned short* dp = &lsA[rl * LDT + tc * 4];
            dp[0] = f2bf(v[0]); dp[1] = f2bf(v[1]); dp[2] = f2bf(v[2]); dp[3] = f2bf(v[3]);
        }
        // ---- stage B (already bf16-transposed, 1 short8/thread) ----
        {
            short8 v = *(const short8*)(W1T + (size_t)(n0 + nb) * 384 + kc + kq);
            *(short8*)&lsB[nb * LDT + kq] = v;
        }
        __syncthreads();
        // ---- MFMA ----
        short8 af[4], bfv[2];
        #pragma unroll
        for (int x = 0; x < 4; x++)
            af[x]  = *(const short8*)&lsA[(wm * 64 + x * 16 + l16) * LDT + quad * 8];
        #pragma unroll
        for (int x = 0; x < 2; x++)
            bfv[x] = *(const short8*)&lsB[(wn * 32 + x * 16 + l16) * LDT + quad * 8];
        #pragma unroll
        for (int i = 0; i < 4; i++)
            #pragma unroll
            for (int j = 0; j < 2; j++)
                acc[i][j] = __builtin_amdgcn_mfma_f32_16x16x32_bf16(af[i], bfv[j], acc[i][j], 0, 0, 0);
        __syncthreads();
    }

    // ---- epilogue: store H1 bf16, accumulate column stats ----
    float s[2] = {0.f, 0.f}, q[2] = {0.f, 0.f};
    #pragma unroll
    for (int i = 0; i < 4; i++) {
        #pragma unroll
        for (int r = 0; r < 4; r++) {
            int row = bm * BM + wm * 64 + i * 16 + quad * 4 + r;
            bool ok = row < E;
            #pragma unroll
            for (int j = 0; j < 2; j++) {
                float v = acc[i][j][r];
                int col = bn * BN + wn * 32 + j * 16 + l16;
                if (ok) {
                    H1[(size_t)row * 256 + col] = f2bf(v);
                    s[j] += v; q[j] += v * v;
                }
            }
        }
    }
    #pragma unroll
    for (int j = 0; j < 2; j++) {
        s[j] += __shfl_xor(s[j], 16, 64); s[j] += __shfl_xor(s[j], 32, 64);
        q[j] += __shfl_xor(q[j], 16, 64); q[j] += __shfl_xor(q[j], 32, 64);
    }
    if (quad == 0) {
        #pragma unroll
        for (int j = 0; j < 2; j++) { ldsS[w][j * 16 + l16] = s[j]; ldsQ[w][j * 16 + l16] = q[j]; }
    }
    __syncthreads();
    if (t < 128) {
        int g = t >> 5, i = t & 31;            // wn group, col-in-group
        float S = ldsS[g][i] + ldsS[4 + g][i]; // wm=0 + wm=1
        float Q = ldsQ[g][i] + ldsQ[4 + g][i];
        int col = bn * BN + t;
        psum[(size_t)col * MT + bm] = S;
        psq [(size_t)col * MT + bm] = Q;
    }
}

// ---- reduce partials -> per-column affine a = g*rsqrt(v+eps), d = b - m*a ----
__global__ __launch_bounds__(256) void stats_kernel(
    const float* __restrict__ psum, const float* __restrict__ psq,
    const float* __restrict__ gamma, const float* __restrict__ beta,
    float* __restrict__ ad, int MT, float invE)
{
    __shared__ float rs[4], rq[4];
    int c = blockIdx.x;
    float s = 0.f, q = 0.f;
    for (int i = threadIdx.x; i < MT; i += 256) {
        s += psum[(size_t)c * MT + i];
        q += psq [(size_t)c * MT + i];
    }
    for (int off = 32; off >= 1; off >>= 1) {
        s += __shfl_xor(s, off, 64);
        q += __shfl_xor(q, off, 64);
    }
    int lane = threadIdx.x & 63, w = threadIdx.x >> 6;
    if (lane == 0) { rs[w] = s; rq[w] = q; }
    __syncthreads();
    if (threadIdx.x == 0) {
        float S = rs[0] + rs[1] + rs[2] + rs[3];
        float Q = rq[0] + rq[1] + rq[2] + rq[3];
        float m = S * invE;
        float v = Q * invE - m * m;
        float a = gamma[c] * rsqrtf(v + 1e-5f);
        ad[c] = a;
        ad[256 + c] = beta[c] - m * a;
    }
}

// ---- GEMM2: relu(a1*H1+d1) @ W2 -> out (pre-BN fp32) + column partials ----
// Same 8-wave 64x32-tile structure as gemm1.
__global__ __launch_bounds__(512, 4) void gemm2_kernel(
    const unsigned short* __restrict__ H1, const unsigned short* __restrict__ W2T,
    const float* __restrict__ ad1, float* __restrict__ out,
    float* __restrict__ psum, float* __restrict__ psq, int E, int MT)
{
    __shared__ __align__(16) unsigned short lsA[BM * LDT];
    __shared__ __align__(16) unsigned short lsB[BN * LDT];
    __shared__ float ldsS[8][32];
    __shared__ float ldsQ[8][32];

    const int t = threadIdx.x;
    const int bm = blockIdx.x, bn = blockIdx.y;
    const int lane = t & 63, w = t >> 6;
    const int wm = w >> 2, wn = w & 3;
    const int quad = lane >> 4, l16 = lane & 15;

    float4v acc[4][2] = {};

    const int kq = (t & 3) * 8, rb = t >> 2;   // 4 col-groups, 128 rows
    const int n0 = bn * BN;

    for (int kk = 0; kk < 8; kk++) {
        const int kc = kk * BK;
        float4v aLo = *(const float4v*)(ad1 + kc + kq);
        float4v aHi = *(const float4v*)(ad1 + kc + kq + 4);
        float4v dLo = *(const float4v*)(ad1 + 256 + kc + kq);
        float4v dHi = *(const float4v*)(ad1 + 256 + kc + kq + 4);
        // ---- stage A: bf16 H1 -> affine+relu -> bf16 (1 row/thread) ----
        {
            int grow = bm * BM + rb; if (grow >= E) grow = E - 1;
            short8 hv = *(const short8*)(H1 + (size_t)grow * 256 + kc + kq);
            short8 yv;
            #pragma unroll
            for (int e = 0; e < 4; e++) {
                float y = fmaxf(fmaf(bf2f((unsigned short)hv[e]), aLo[e], dLo[e]), 0.f);
                yv[e] = (short)f2bf(y);
            }
            #pragma unroll
            for (int e = 0; e < 4; e++) {
                float y = fmaxf(fmaf(bf2f((unsigned short)hv[4 + e]), aHi[e], dHi[e]), 0.f);
                yv[4 + e] = (short)f2bf(y);
            }
            *(short8*)&lsA[rb * LDT + kq] = yv;
        }
        // ---- stage B (1 short8/thread) ----
        {
            short8 v = *(const short8*)(W2T + (size_t)(n0 + rb) * 256 + kc + kq);
            *(short8*)&lsB[rb * LDT + kq] = v;
        }
        __syncthreads();
        short8 af[4], bfv[2];
        #pragma unroll
        for (int x = 0; x < 4; x++)
            af[x]  = *(const short8*)&lsA[(wm * 64 + x * 16 + l16) * LDT + quad * 8];
        #pragma unroll
        for (int x = 0; x < 2; x++)
            bfv[x] = *(const short8*)&lsB[(wn * 32 + x * 16 + l16) * LDT + quad * 8];
        #pragma unroll
        for (int i = 0; i < 4; i++)
            #pragma unroll
            for (int j = 0; j < 2; j++)
                acc[i][j] = __builtin_amdgcn_mfma_f32_16x16x32_bf16(af[i], bfv[j], acc[i][j], 0, 0, 0);
        __syncthreads();
    }

    float s[2] = {0.f, 0.f}, q[2] = {0.f, 0.f};
    #pragma unroll
    for (int i = 0; i < 4; i++) {
        #pragma unroll
        for (int r = 0; r < 4; r++) {
            int row = bm * BM + wm * 64 + i * 16 + quad * 4 + r;
            bool ok = row < E;
            #pragma unroll
            for (int j = 0; j < 2; j++) {
                float v = acc[i][j][r];
                int col = bn * BN + wn * 32 + j * 16 + l16;
                if (ok) {
                    out[(size_t)row * 256 + col] = v;
                    s[j] += v; q[j] += v * v;
                }
            }
        }
    }
    #pragma unroll
    for (int j = 0; j < 2; j++) {
        s[j] += __shfl_xor(s[j], 16, 64); s[j] += __shfl_xor(s[j], 32, 64);
        q[j] += __shfl_xor(q[j], 16, 64); q[j] += __shfl_xor(q[j], 32, 64);
    }
    if (quad == 0) {
        #pragma unroll
        for (int j = 0; j < 2; j++) { ldsS[w][j * 16 + l16] = s[j]; ldsQ[w][j * 16 + l16] = q[j]; }
    }
    __syncthreads();
    if (t < 128) {
        int g = t >> 5, i = t & 31;
        float S = ldsS[g][i] + ldsS[4 + g][i];
        float Q = ldsQ[g][i] + ldsQ[4 + g][i];
        int col = bn * BN + t;
        psum[(size_t)col * MT + bm] = S;
        psq [(size_t)col * MT + bm] = Q;
    }
}

// ---- out = a2*out + d2 (in place) ----
__global__ __launch_bounds__(256) void finalize_kernel(
    float* __restrict__ out, const float* __restrict__ ad, long n4)
{
    long stride = (long)gridDim.x * 256;
    for (long i = (long)blockIdx.x * 256 + threadIdx.x; i < n4; i += stride) {
        float4v v = ((float4v*)out)[i];
        int c4 = (int)(i & 63);
        float4v a = ((const float4v*)ad)[c4];
        float4v d = ((const float4v*)(ad + 256))[c4];
        v = a * v + d;
        ((float4v*)out)[i] = v;
    }
}

extern "C" void kernel_launch(void* const* d_in, const int* in_sizes, int n_in,
                              void* d_out, int out_size, void* d_ws, size_t ws_size,
                              hipStream_t stream)
{
    const float* src  = (const float*)d_in[0];
    const float* dst  = (const float*)d_in[1];
    const float* edge = (const float*)d_in[2];
    const float* u    = (const float*)d_in[3];
    const int*   batch= (const int*)d_in[4];
    const float* W1   = (const float*)d_in[5];
    const float* g1   = (const float*)d_in[6];
    const float* b1   = (const float*)d_in[7];
    const float* W2   = (const float*)d_in[8];
    const float* g2   = (const float*)d_in[9];
    const float* b2   = (const float*)d_in[10];
    float* out = (float*)d_out;

    const int E  = in_sizes[0] / 128;
    const int MT = (E + BM - 1) / BM;

    char* ws = (char*)d_ws;
    size_t off = 0;
    auto alloc = [&](size_t bytes) -> void* {
        void* p = (void*)(ws + off);
        off += (bytes + 255) & ~(size_t)255;
        return p;
    };
    unsigned short* H1  = (unsigned short*)alloc((size_t)E * 256 * 2);
    unsigned short* W1T = (unsigned short*)alloc((size_t)256 * 384 * 2);
    unsigned short* W2T = (unsigned short*)alloc((size_t)256 * 256 * 2);
    float* psum = (float*)alloc((size_t)256 * MT * 4);
    float* psq  = (float*)alloc((size_t)256 * MT * 4);
    float* ad1  = (float*)alloc(512 * 4);
    float* ad2  = (float*)alloc(512 * 4);
    (void)ws_size; (void)n_in; (void)out_size;

    transpose_bf16_kernel<<<(384 * 256 + 255) / 256, 256, 0, stream>>>(W1, W1T, 384, 256);
    transpose_bf16_kernel<<<(256 * 256 + 255) / 256, 256, 0, stream>>>(W2, W2T, 256, 256);
    gemm1_kernel<<<dim3(MT, 2), 512, 0, stream>>>(src, dst, edge, u, batch, W1T, H1, psum, psq, E, MT);
    stats_kernel<<<256, 256, 0, stream>>>(psum, psq, g1, b1, ad1, MT, 1.0f / (float)E);
    gemm2_kernel<<<dim3(MT, 2), 512, 0, stream>>>(H1, W2T, ad1, out, psum, psq, E, MT);
    stats_kernel<<<256, 256, 0, stream>>>(psum, psq, g2, b2, ad2, MT, 1.0f / (float)E);
    const long n4 = (long)E * 64;
    finalize_kernel<<<16384, 256, 0, stream>>>(out, ad2, n4);
}